// Round 14
// baseline (245.523 us; speedup 1.0000x reference)
//
#include <hip/hip_runtime.h>
#include <cmath>

// PhaseAwareClassifier on MI355X — R31: l-fold + persistent conn register
// cache at 1 wave/SIMD.
// R30 post-mortem: fold verified (157.9us, conflicts 5.3M->2.7M = the
// predicted /2, absmax bit-identical). Wall = 3 rounds of ~52.6us.
// R31: the fold unlocked the regime the conn-cache always needed. conn
// A-frags are task- AND time-invariant; at (256,1) the budget is ~512
// (R22/R28 calibration; m08 clean through 450). Cache kt 0..2 = 54 bf16x8
// = 216 VGPR loaded ONCE, reused for every task and every t-step. kt 3,4
// stay on the LDS path (single bank, unroll(1), sched_barrier(0) fence so
// the transient bank doesn't stack on the cache -> peak ~390 < 450).
// Per-step LDS reads 110 -> ~48/wave: tasks become MFMA+epilogue issue-
// bound, which a SINGLE wave drives fine (R22's 1/SIMD failure was load
// latency; A is now in registers). Packing: 1024 workers, 4224 tasks ->
// 4 rounds + blocks 0..31 take a 5th (full 4-wave blocks, no stragglers).
// Bit-exact: per-acc MFMA order kt-ascending, same CPAIR order, identical
// float sequences everywhere (absmax 0.0078125 since R17).
// Tripwire: VGPR ~330-410 + WRITE < 2MB = clean; spill -> revert R30.
// LDS: conn 82,944 + OBP 36,864 + gsp 576 = 120,384 B -> 1 block/CU.

#define NSTEPS  10
#define INJ_ST  4
#define MT      144          // padded M (9 tiles of 16)
#define NTASK   4224         // 33 unique l x 128 images

typedef __bf16 bf16x8 __attribute__((ext_vector_type(8)));
typedef __bf16 bf16x4 __attribute__((ext_vector_type(4)));
typedef short  short8 __attribute__((ext_vector_type(8)));
typedef float  f32x4  __attribute__((ext_vector_type(4)));

// workspace layout (float offsets)
#define WS_MAX    0          // 1      enc_max (uint-ordered float)
#define WS_ENERGY 64         // 1280   energy[b][10]
#define WS_GSP    2048       // 144    g2q[j] = -0.5*log2(e)*softplus(gain)
#define WS_CONN   4096       // 2 bf16 mats [20][144][8] chunked: Cr, Ci

// fused prep: blocks 0..97 = image absmax; blocks 98.. = conn + gsp tables
__global__ void k_pre(const float* __restrict__ img,
                      const float* __restrict__ cr, const float* __restrict__ ci,
                      const float* __restrict__ phase, const float* __restrict__ gain,
                      float* ws) {
    if (blockIdx.x < 98) {
        __shared__ float sm[256];
        float v = 0.f;
        for (int i = blockIdx.x * 256 + threadIdx.x; i < 128 * 28 * 28; i += 98 * 256)
            v = fmaxf(v, fabsf(img[i]));
        sm[threadIdx.x] = v;
        __syncthreads();
        for (int s = 128; s > 0; s >>= 1) {
            if (threadIdx.x < s) sm[threadIdx.x] = fmaxf(sm[threadIdx.x], sm[threadIdx.x + s]);
            __syncthreads();
        }
        if (threadIdx.x == 0)
            atomicMax((unsigned int*)(ws + WS_MAX), __float_as_uint(sm[0]));
        return;
    }
    int i = (blockIdx.x - 98) * 256 + threadIdx.x;
    __bf16* Cb = (__bf16*)(ws + WS_CONN);
    const int NCE = MT * 160;              // 23040 (m,k) pairs
    if (i < NCE) {
        int m = i / 160, k = i % 160;
        float vr = 0.f, vi = 0.f;
        if (m < 131 && k < 131) {
            float a = cr[k * 131 + m], b = ci[k * 131 + m];
            float ph = phase[m];
            float cp = cosf(ph), sp = sinf(ph);
            vr = a * cp - b * sp;
            vi = a * sp + b * cp;
        }
        int ca = ((k >> 3) * MT + m) * 8 + (k & 7);    // chunked addr
        Cb[ca]       = (__bf16)vr;
        Cb[NCE + ca] = (__bf16)vi;
    } else if (i < NCE + MT) {
        int j = i - NCE;
        float g = 0.f;
        if (j < 131) {
            float x = gain[j];
            g = (x > 20.f) ? x : log1pf(expf(x));  // softplus
        }
        ws[WS_GSP + j] = g * -0.72134754543f;       // -2*log2(e)*g / 4
    }
}

static __device__ __forceinline__ f32x4 MF(bf16x8 a, bf16x8 b, f32x4 c) {
    return __builtin_amdgcn_mfma_f32_16x16x32_bf16(a, b, c, 0, 0, 0);
}
static __device__ __forceinline__ bf16x8 bneg(bf16x8 a) {
    short8 t = __builtin_bit_cast(short8, a) ^ (short8)(short)0x8000;
    return __builtin_bit_cast(bf16x8, t);
}

// one complex 16x16 tile accumulation; order identical to R17..R30.
#define CPAIR(AR, AI, BR, BI, BNI, P)                                  \
    accr[P] = MF(AR, BR,  accr[P]);                                    \
    accr[P] = MF(AI, BNI, accr[P]);                                    \
    acci[P] = MF(AR, BI,  acci[P]);                                    \
    acci[P] = MF(AI, BR,  acci[P]);

__global__ __launch_bounds__(256, 1)
void k_main(const float* __restrict__ img, const float* __restrict__ ws,
            float* __restrict__ energy) {
    __shared__ __bf16 CrL[18 * MT * 8];            // 41,472 B
    __shared__ __bf16 CiL[18 * MT * 8];            // 41,472 B
    __shared__ __bf16 OBP[2][4][18 * 16 * 8];      // 36,864 B  [r/i][wave][...]
    __shared__ float  gspL[144];                   // 576 B
    // total 120,384 B -> 1 block/CU, 4 waves = 1/SIMD (registers bind).

    const int tid  = threadIdx.x;
    const int lane = tid & 63;
    const int ln15 = lane & 15;
    const int quad = lane >> 4;
    const int w    = __builtin_amdgcn_readfirstlane(tid >> 6);  // 0..3

    __bf16* __restrict__ OWr = &OBP[0][w][0];
    __bf16* __restrict__ OWi = &OBP[1][w][0];

    // injection scaling (identical rounding chain to R20..R30)
    const float mx = ws[WS_MAX];
    const float sc = (mx > 1e-8f) ? (1.02f / mx) : 1.02f;   // 0.85*4*0.3

    // stage conn chunks 0..17 + gsp -> LDS (the ONLY barrier in the kernel)
    {
        const int4* srcR = (const int4*)(ws + WS_CONN);
        const int4* srcI = (const int4*)(ws + WS_CONN + (MT * 160 / 2));
        int4* dstR = (int4*)CrL;
        int4* dstI = (int4*)CiL;
        for (int i = tid; i < 2592; i += 256) { dstR[i] = srcR[i]; dstI[i] = srcI[i]; }
        if (tid < 144) gspL[tid] = ws[WS_GSP + tid];
    }
    __syncthreads();                                // conn + gsp staged

    // ---- persistent conn register cache: kt 0..2, chunk kt*4+quad.
    // 54 bf16x8 = 216 VGPR; task- and time-invariant, loaded once. ----
    bf16x8 cR[3][9], cI[3][9];
#pragma unroll
    for (int kt = 0; kt < 3; ++kt) {
        const int ab = ((kt * 4 + quad) * MT + ln15) * 8;
#pragma unroll
        for (int mt = 0; mt < 9; ++mt) {
            cR[kt][mt] = *(const bf16x8*)(CrL + ab + mt * 128);
            cI[kt][mt] = *(const bf16x8*)(CiL + ab + mt * 128);
        }
    }

    // ---- wave-task loop: T -> (u = T>>7 in 0..32, im = T&127).
    // 1024 workers; r=0..3 full; r=4 only blocks 0..31 (full 4-wave). ----
#pragma unroll 1
    for (int r = 0; r < 5; ++r) {
        const int T = r * 1024 + blockIdx.x * 4 + w;
        if (T >= NTASK) break;                      // wave-uniform
        const int u  = T >> 7;                      // unique l (0..32)
        const int im = T & 127;
        const float wl  = 1.0f - fabsf((float)u - 32.0f) * (1.0f / 64.0f);
        const float wgt = (u == 0 || u == 32) ? 1.0f : 2.0f;  // mirror count
        const int imgb = im * 784 + (ln15 >> 2) * 28 + (ln15 & 3);

        f32x4 accr[9], acci[9];                     // p = mt
#pragma unroll
        for (int p = 0; p < 9; ++p) { accr[p] = (f32x4)0.f; acci[p] = (f32x4)0.f; }

        // injection: rows j<49 (tiles 0..3)
        auto inj_add = [&]() {
#pragma unroll
            for (int mt = 0; mt < 4; ++mt) {
#pragma unroll
                for (int rr = 0; rr < 4; ++rr) {
                    int j = mt * 16 + quad * 4 + rr;
                    if (j < 49) {
                        int pi = j / 7, pj = j % 7;
                        float px = img[imgb + pi * 112 + pj * 4];
                        float t  = px * sc;
                        accr[mt][rr] = fmaf(t, wl, accr[mt][rr]);
                    }
                }
            }
        };

        // epilogue: out = a * tanh(g*|f|)/|f| (0.25 folded), write own OB
        auto epilogue = [&]() {
#pragma unroll
            for (int mt = 0; mt < 9; ++mt) {
                f32x4 g2v = *(const f32x4*)(gspL + mt * 16 + quad * 4);
                bf16x4 pr, pi;
#pragma unroll
                for (int rr = 0; rr < 4; ++rr) {
                    float ar = accr[mt][rr], ai = acci[mt][rr];
                    float mag2 = fmaf(ar, ar, fmaf(ai, ai, 1.6e-7f));
                    float rsq  = __builtin_amdgcn_rsqf(mag2);
                    float e    = __builtin_amdgcn_exp2f(g2v[rr] * (mag2 * rsq));
                    float uu   = __builtin_amdgcn_rcpf(1.0f + e);
                    float th   = fmaf(-2.0f, e * uu, 1.0f);
                    float scv  = th * rsq;
                    pr[rr] = (__bf16)(ar * scv); pi[rr] = (__bf16)(ai * scv);
                }
                const int off = ((mt * 2 + (quad >> 1)) * 16 + ln15) * 8
                              + (quad & 1) * 4;
                *(bf16x4*)(OWr + off) = pr;
                *(bf16x4*)(OWi + off) = pi;
            }
        };

        inj_add();                                  // t = 0 (out is zero)
        epilogue();                                 // wave-private, no barrier

        // ---- time loop: zero barriers; kt0..2 cached, kt3..4 LDS ----
#pragma unroll 1
        for (int t = 1; t < NSTEPS - 1; ++t) {
#pragma unroll
            for (int p = 0; p < 9; ++p) { accr[p] *= 0.85f; acci[p] *= 0.85f; }
            if (t < INJ_ST) inj_add();

            if (t == 1) {
                // out(0) rows >=49 exactly zero -> kt 0,1 only (cached)
#pragma unroll
                for (int kt = 0; kt < 2; ++kt) {
                    const int bb = ((kt * 4 + quad) * 16 + ln15) * 8;
                    bf16x8 br = *(const bf16x8*)(OWr + bb);
                    bf16x8 bi = *(const bf16x8*)(OWi + bb);
                    bf16x8 bn = bneg(bi);
#pragma unroll
                    for (int mt = 0; mt < 9; ++mt) {
                        CPAIR(cR[kt][mt], cI[kt][mt], br, bi, bn, mt)
                    }
                }
            } else {
                // kt 0..2: A from the persistent cache, B from own OB
#pragma unroll
                for (int kt = 0; kt < 3; ++kt) {
                    const int bb = ((kt * 4 + quad) * 16 + ln15) * 8;
                    bf16x8 br = *(const bf16x8*)(OWr + bb);
                    bf16x8 bi = *(const bf16x8*)(OWi + bb);
                    bf16x8 bn = bneg(bi);
#pragma unroll
                    for (int mt = 0; mt < 9; ++mt) {
                        CPAIR(cR[kt][mt], cI[kt][mt], br, bi, bn, mt)
                    }
                }
                // fence: keep the kt3/4 LDS bank from stacking on the cache
                __builtin_amdgcn_sched_barrier(0);
                // kt 3,4: LDS path, single bank (unroll(1): R15 discipline)
#pragma unroll 1
                for (int kt = 3; kt < 5; ++kt) {
                    const int kch = kt * 4 + quad;
                    const int rk  = (kch > 17) ? 17 : kch;
                    const int bb  = (rk * 16 + ln15) * 8;
                    bf16x8 br = *(const bf16x8*)(OWr + bb);
                    bf16x8 bi = *(const bf16x8*)(OWi + bb);
                    const int ab = (rk * MT + ln15) * 8;
                    bf16x8 ar[9], ai[9];
#pragma unroll
                    for (int mt = 0; mt < 9; ++mt) {
                        ar[mt] = *(const bf16x8*)(CrL + ab + mt * 128);
                        ai[mt] = *(const bf16x8*)(CiL + ab + mt * 128);
                    }
                    bf16x8 bn = bneg(bi);
#pragma unroll
                    for (int mt = 0; mt < 9; ++mt) {
                        CPAIR(ar[mt], ai[mt], br, bi, bn, mt)
                    }
                }
            }
            epilogue();                             // wave-private, no barrier
        }

        // ---- t = 9: only rows 121..130 (tiles 7,8) feed energy ----
        accr[7] *= 0.85f; acci[7] *= 0.85f;
        accr[8] *= 0.85f; acci[8] *= 0.85f;
#pragma unroll
        for (int kt = 0; kt < 3; ++kt) {            // cached part
            const int bb = ((kt * 4 + quad) * 16 + ln15) * 8;
            bf16x8 br = *(const bf16x8*)(OWr + bb);
            bf16x8 bi = *(const bf16x8*)(OWi + bb);
            bf16x8 bn = bneg(bi);
            CPAIR(cR[kt][7], cI[kt][7], br, bi, bn, 7)
            CPAIR(cR[kt][8], cI[kt][8], br, bi, bn, 8)
        }
        __builtin_amdgcn_sched_barrier(0);
#pragma unroll 1
        for (int kt = 3; kt < 5; ++kt) {            // LDS part
            const int kch = kt * 4 + quad;
            const int rk  = (kch > 17) ? 17 : kch;
            const int bb  = (rk * 16 + ln15) * 8;
            bf16x8 br = *(const bf16x8*)(OWr + bb);
            bf16x8 bi = *(const bf16x8*)(OWi + bb);
            const int ab = (rk * MT + ln15) * 8;
            bf16x8 ar7 = *(const bf16x8*)(CrL + ab + 7 * 128);
            bf16x8 ai7 = *(const bf16x8*)(CiL + ab + 7 * 128);
            bf16x8 ar8 = *(const bf16x8*)(CrL + ab + 8 * 128);
            bf16x8 ai8 = *(const bf16x8*)(CiL + ab + 8 * 128);
            bf16x8 bn = bneg(bi);
            CPAIR(ar7, ai7, br, bi, bn, 7)
            CPAIR(ar8, ai8, br, bi, bn, 8)
        }

        // ---- energy: per-lane |out|^2, quad shfl-reduce over 16 cols,
        // one atomicAdd per (j), weighted by mirror multiplicity ----
#pragma unroll
        for (int mt = 7; mt < 9; ++mt) {
#pragma unroll
            for (int rr = 0; rr < 4; ++rr) {
                int j = mt * 16 + quad * 4 + rr;
                if (j >= 121 && j <= 130) {
                    float ar = accr[mt][rr], ai = acci[mt][rr];
                    float mag2 = fmaf(ar, ar, fmaf(ai, ai, 1.6e-7f));
                    float rsq  = __builtin_amdgcn_rsqf(mag2);
                    float e    = __builtin_amdgcn_exp2f(gspL[j] * (mag2 * rsq));
                    float uu   = __builtin_amdgcn_rcpf(1.0f + e);
                    float th   = fmaf(-2.0f, e * uu, 1.0f);
                    float scv  = th * rsq;
                    float orv = ar * scv, oiv = ai * scv;
                    float e2 = orv * orv + oiv * oiv;
                    e2 += __shfl_xor(e2, 1);
                    e2 += __shfl_xor(e2, 2);
                    e2 += __shfl_xor(e2, 4);
                    e2 += __shfl_xor(e2, 8);
                    if (ln15 == 0)
                        atomicAdd(energy + im * 10 + (j - 121), e2 * wgt);
                }
            }
        }
    }
}

__global__ void k_readout(const float* __restrict__ ws,
                          const float* __restrict__ W,
                          const float* __restrict__ bias,
                          float* __restrict__ out) {
    int i = blockIdx.x * 256 + threadIdx.x;
    if (i < 1280) {
        int b = i / 10, o = i % 10;
        float s = bias[o];
#pragma unroll
        for (int f = 0; f < 10; ++f) {
            float feat = log1pf(ws[WS_ENERGY + b * 10 + f] + 1e-8f);
            s = fmaf(feat, W[o * 10 + f], s);
        }
        out[i] = s;
    }
}

extern "C" void kernel_launch(void* const* d_in, const int* in_sizes, int n_in,
                              void* d_out, int out_size, void* d_ws, size_t ws_size,
                              hipStream_t stream) {
    const float* images = (const float*)d_in[0];
    const float* conn_r = (const float*)d_in[1];
    const float* conn_i = (const float*)d_in[2];
    const float* phase  = (const float*)d_in[3];
    const float* gain   = (const float*)d_in[4];
    const float* W      = (const float*)d_in[5];
    const float* bias   = (const float*)d_in[6];
    float* ws  = (float*)d_ws;
    float* out = (float*)d_out;

    // zero WS_MAX + energy (floats 0..1343) — stream-ordered, capture-safe
    hipMemsetAsync(ws, 0, (WS_ENERGY + 1280) * sizeof(float), stream);
    hipLaunchKernelGGL(k_pre, dim3(189), dim3(256), 0, stream,
                       images, conn_r, conn_i, phase, gain, ws);
    hipLaunchKernelGGL(k_main, dim3(256), dim3(256), 0, stream,
                       images, ws, ws + WS_ENERGY);
    hipLaunchKernelGGL(k_readout, dim3(5), dim3(256), 0, stream, ws, W, bias, out);
}